// Round 8
// baseline (399.224 us; speedup 1.0000x reference)
//
#include <hip/hip_runtime.h>
#include <hip/hip_bf16.h>
#include <math.h>

typedef _Float16 f16x8 __attribute__((ext_vector_type(8)));
typedef _Float16 f16x4 __attribute__((ext_vector_type(4)));
typedef float    f32x4 __attribute__((ext_vector_type(4)));

#define DIMD    256
#define MT      64          // rows per block
#define BT      256         // 4 waves; each wave owns 16 rows x 256 cols
#define KSTEPS  26
#define EXP_C   7.2134752044448170f   // log2(e)/TEMP, TEMP=0.2
#define LOG2E   1.4426950408889634f   // 0.2*EXP_C, for z-recovery
#define INV_1MP 1.1111111111111112f   // 1/(1-P), P=0.1

// ---- DPP row_ror cross-lane (16-lane groups, no DS ops) ------------------
template<int CTRL>
static __device__ __forceinline__ float dpp_ror(float s) {
    return __builtin_bit_cast(float, __builtin_amdgcn_update_dpp(
        0, __builtin_bit_cast(int, s), CTRL, 0xf, 0xf, false));
}
static __device__ __forceinline__ float row16_sum(float s) {
    s += dpp_ror<0x128>(s);   // ror:8
    s += dpp_ror<0x124>(s);   // ror:4
    s += dpp_ror<0x122>(s);   // ror:2
    s += dpp_ror<0x121>(s);   // ror:1
    return s;
}
static __device__ __forceinline__ float row16_max(float m) {
    m = fmaxf(m, dpp_ror<0x128>(m));
    m = fmaxf(m, dpp_ror<0x124>(m));
    m = fmaxf(m, dpp_ror<0x122>(m));
    m = fmaxf(m, dpp_ror<0x121>(m));
    return m;
}

// ---- pre-kernel: W[c][k] fp32 -> frag-major fp16 (single plane) ----------
// Tile (kt,ct): 64 lanes x 8 fp16. Lane l: col=ct*16+(l&15), k=kt*32+(l>>4)*8..+7
// ws: [128 tiles][64 lanes] = 128 KB
__global__ __launch_bounds__(256)
void w_conv_kernel(const float* __restrict__ W, f16x8* __restrict__ ws) {
    int gid  = blockIdx.x * 256 + threadIdx.x;   // 0..8191
    int tile = gid >> 6;                         // kt*16+ct
    int lane = gid & 63;
    int kt = tile >> 4, ct = tile & 15;
    int col = ct * 16 + (lane & 15);
    int k0  = kt * 32 + (lane >> 4) * 8;
    const float* wr = W + col * 256 + k0;
    float4 f01 = *(const float4*)wr;
    float4 f23 = *(const float4*)(wr + 4);
    float wv[8] = {f01.x, f01.y, f01.z, f01.w, f23.x, f23.y, f23.z, f23.w};
    f16x8 hi;
    #pragma unroll
    for (int j = 0; j < 8; ++j) hi[j] = (_Float16)wv[j];
    ws[tile * 64 + lane] = hi;
}

// ---- main fused kernel ----------------------------------------------------
// LDS: A fp16 [64 rows][256 cols], 32 KB (5 blocks/CU = 160 KiB exactly),
// byte-XOR swizzle: byte = row*512 + ((col*2) ^ ((row&7)<<4))
__global__ __launch_bounds__(BT, 5)
void sad_mfma_kernel(const float* __restrict__ feat,
                     const float* __restrict__ bias,
                     const f16x8* __restrict__ ws,
                     float* __restrict__ out,
                     int N)
{
    __shared__ __align__(16) unsigned char smem[MT * 512];  // 32 KB

    const int tid  = threadIdx.x;
    const int lane = tid & 63;
    const int wv   = tid >> 6;           // wave 0..3, owns rows wv*16..+15
    const long long n0 = (long long)blockIdx.x * MT;

    // ---- stage 64 feature rows -> fp16 LDS (swizzled) ----
    const float4* fvec = (const float4*)feat;
    #pragma unroll
    for (int i = 0; i < 16; ++i) {
        int flat4 = i * BT + tid;            // float4 index over [64 rows][64 f4]
        int row = flat4 >> 6;
        int c4  = flat4 & 63;
        long long grow = n0 + row;
        if (grow >= N) grow = N - 1;
        float4 f = fvec[grow * 64 + c4];
        f16x4 h4;
        h4[0] = (_Float16)f.x; h4[1] = (_Float16)f.y;
        h4[2] = (_Float16)f.z; h4[3] = (_Float16)f.w;
        int off = row * 512 + ((c4 * 8) ^ ((row & 7) << 4));
        *(f16x4*)(smem + off) = h4;
    }
    __syncthreads();

    // ---- GEMM: acc[ct][p] -> col = ct*16+(lane&15), row = wv*16+(lane>>4)*4+p
    f32x4 acc[16];
    #pragma unroll
    for (int ct = 0; ct < 16; ++ct) {
        float b = bias[ct * 16 + (lane & 15)];
        acc[ct] = f32x4{b, b, b, b};
    }

    const int arow  = wv * 16 + (lane & 15);
    const int swzA  = (arow & 7) << 4;
    const int abase = arow * 512;
    const int kgrp  = (lane >> 4) * 16;

    #pragma unroll
    for (int kt = 0; kt < 8; ++kt) {
        int kbyte = kt * 64 + kgrp;
        f16x8 a8 = *(const f16x8*)(smem + abase + (kbyte ^ swzA));
        #pragma unroll
        for (int ct = 0; ct < 16; ++ct) {
            f16x8 bh = ws[(kt * 16 + ct) * 64 + lane];
            acc[ct] = __builtin_amdgcn_mfma_f32_16x16x32_f16(a8, bh, acc[ct], 0, 0, 0);
        }
    }

    // ---- row max per plane: 16 cts in-thread + DPP 16-lane reduce ----
    float M[4];
    #pragma unroll
    for (int p = 0; p < 4; ++p) {
        float m = acc[0][p];
        #pragma unroll
        for (int ct = 1; ct < 16; ++ct) m = fmaxf(m, acc[ct][p]);
        M[p] = row16_max(m);
    }

    // ---- plane pairs: q-form peel (state = q only; le5 recomputed at end) --
    #pragma unroll
    for (int pp = 0; pp < 2; ++pp) {
        const int p0 = 2 * pp, p1 = p0 + 1;

        float qa[16], qb[16];
        #pragma unroll
        for (int j = 0; j < 16; ++j) {
            qa[j] = __builtin_amdgcn_exp2f((acc[j][p0] - M[p0]) * EXP_C);
            qb[j] = __builtin_amdgcn_exp2f((acc[j][p1] - M[p1]) * EXP_C);
        }

        // 26 peeling steps on q = E*z^5:  S=sum(q); r=1-q/S; q *= r^5
        #pragma unroll 1
        for (int it = 0; it < KSTEPS; ++it) {
            float sa0 = ((qa[0] + qa[1]) + (qa[2] + qa[3]))
                      + ((qa[4] + qa[5]) + (qa[6] + qa[7]));
            float sa1 = ((qa[8] + qa[9]) + (qa[10] + qa[11]))
                      + ((qa[12] + qa[13]) + (qa[14] + qa[15]));
            float sb0 = ((qb[0] + qb[1]) + (qb[2] + qb[3]))
                      + ((qb[4] + qb[5]) + (qb[6] + qb[7]));
            float sb1 = ((qb[8] + qb[9]) + (qb[10] + qb[11]))
                      + ((qb[12] + qb[13]) + (qb[14] + qb[15]));
            float sa = row16_sum(sa0 + sa1);
            float sb = row16_sum(sb0 + sb1);
            sa = fmaxf(sa, 1e-30f);
            sb = fmaxf(sb, 1e-30f);
            float na = -__builtin_amdgcn_rcpf(sa);
            float nb = -__builtin_amdgcn_rcpf(sb);
            #pragma unroll
            for (int j = 0; j < 16; ++j) {
                float ra  = fmaf(qa[j], na, 1.0f);
                float rb  = fmaf(qb[j], nb, 1.0f);
                float ra2 = ra * ra;
                float rb2 = rb * rb;
                float ra4 = ra2 * ra2;
                float rb4 = rb2 * rb2;
                qa[j] *= ra4 * ra;
                qb[j] *= rb4 * rb;
            }
        }

        // epilogue both planes: z = exp2(0.2*log2(q) - le5); out = f*z/(1-P)
        #pragma unroll
        for (int half = 0; half < 2; ++half) {
            int p = half ? p1 : p0;
            const float* q = half ? qb : qa;
            int row = wv * 16 + (lane >> 4) * 4 + p;
            long long grow = n0 + row;
            if (grow < N) {
                int swz = (row & 7) << 4;
                float* orow = out + grow * 256;
                #pragma unroll
                for (int j = 0; j < 16; ++j) {
                    int col = j * 16 + (lane & 15);
                    float le5 = (acc[j][p] - M[p]) * LOG2E;
                    float qv  = fmaxf(q[j], 1e-38f);
                    float zz  = __builtin_amdgcn_exp2f(
                        fmaf(__builtin_amdgcn_logf(qv), 0.2f, -le5));
                    int off = row * 512 + ((col * 2) ^ swz);
                    float fval = (float)(*(const _Float16*)(smem + off));
                    orow[col] = fval * (zz * INV_1MP);
                }
            }
        }
    }
}

extern "C" void kernel_launch(void* const* d_in, const int* in_sizes, int n_in,
                              void* d_out, int out_size, void* d_ws, size_t ws_size,
                              hipStream_t stream) {
    const float* feat = (const float*)d_in[0];
    const float* W    = (const float*)d_in[1];
    const float* bias = (const float*)d_in[2];
    float* out = (float*)d_out;
    int N = in_sizes[0] / DIMD;

    // 1) W -> frag-major fp16 in workspace (128 KB)
    w_conv_kernel<<<32, 256, 0, stream>>>(W, (f16x8*)d_ws);

    // 2) fused mask-GEMM + paired q-form peeling + output
    int grid = (int)((N + MT - 1) / MT);
    sad_mfma_kernel<<<grid, BT, 0, stream>>>(feat, bias, (const f16x8*)d_ws, out, N);
}

// Round 9
// 380.229 us; speedup vs baseline: 1.0500x; 1.0500x over previous
//
#include <hip/hip_runtime.h>
#include <hip/hip_bf16.h>
#include <math.h>

typedef _Float16 f16x8 __attribute__((ext_vector_type(8)));
typedef _Float16 f16x4 __attribute__((ext_vector_type(4)));
typedef float    f32x4 __attribute__((ext_vector_type(4)));

#define DIMD    256
#define MT      64          // rows per block
#define BT      256         // 4 waves; each wave owns 16 rows x 256 cols
#define KSTEPS  26
#define EXP_C   7.2134752044448170f   // log2(e)/TEMP, TEMP=0.2
#define LOG2E   1.4426950408889634f   // 0.2*EXP_C, for z-recovery
#define INV_1MP 1.1111111111111112f   // 1/(1-P), P=0.1

// ---- DPP row_ror cross-lane (16-lane groups, no DS ops) ------------------
template<int CTRL>
static __device__ __forceinline__ float dpp_ror(float s) {
    return __builtin_bit_cast(float, __builtin_amdgcn_update_dpp(
        0, __builtin_bit_cast(int, s), CTRL, 0xf, 0xf, false));
}
static __device__ __forceinline__ float row16_sum(float s) {
    s += dpp_ror<0x128>(s);   // ror:8
    s += dpp_ror<0x124>(s);   // ror:4
    s += dpp_ror<0x122>(s);   // ror:2
    s += dpp_ror<0x121>(s);   // ror:1
    return s;
}
static __device__ __forceinline__ float row16_max(float m) {
    m = fmaxf(m, dpp_ror<0x128>(m));
    m = fmaxf(m, dpp_ror<0x124>(m));
    m = fmaxf(m, dpp_ror<0x122>(m));
    m = fmaxf(m, dpp_ror<0x121>(m));
    return m;
}

// ---- pre-kernel: W[c][k] fp32 -> frag-major fp16 (single plane) ----------
// Tile (kt,ct): 64 lanes x 8 fp16. Lane l: col=ct*16+(l&15), k=kt*32+(l>>4)*8..+7
// ws: [128 tiles][64 lanes] = 128 KB
__global__ __launch_bounds__(256)
void w_conv_kernel(const float* __restrict__ W, f16x8* __restrict__ ws) {
    int gid  = blockIdx.x * 256 + threadIdx.x;   // 0..8191
    int tile = gid >> 6;                         // kt*16+ct
    int lane = gid & 63;
    int kt = tile >> 4, ct = tile & 15;
    int col = ct * 16 + (lane & 15);
    int k0  = kt * 32 + (lane >> 4) * 8;
    const float* wr = W + col * 256 + k0;
    float4 f01 = *(const float4*)wr;
    float4 f23 = *(const float4*)(wr + 4);
    float wv[8] = {f01.x, f01.y, f01.z, f01.w, f23.x, f23.y, f23.z, f23.w};
    f16x8 hi;
    #pragma unroll
    for (int j = 0; j < 8; ++j) hi[j] = (_Float16)wv[j];
    ws[tile * 64 + lane] = hi;
}

// ---- main fused kernel ----------------------------------------------------
// LDS: A fp16 [64 rows][256 cols], 32 KB, byte-XOR swizzle:
//   byte = row*512 + ((col*2) ^ ((row&7)<<4))
__global__ __launch_bounds__(BT, 4)
void sad_mfma_kernel(const float* __restrict__ feat,
                     const float* __restrict__ bias,
                     const f16x8* __restrict__ ws,
                     float* __restrict__ out,
                     int N)
{
    __shared__ __align__(16) unsigned char smem[MT * 512];  // 32 KB

    const int tid  = threadIdx.x;
    const int lane = tid & 63;
    const int wv   = tid >> 6;           // wave 0..3, owns rows wv*16..+15
    const long long n0 = (long long)blockIdx.x * MT;

    // ---- stage 64 feature rows -> fp16 LDS (swizzled) ----
    const float4* fvec = (const float4*)feat;
    #pragma unroll
    for (int i = 0; i < 16; ++i) {
        int flat4 = i * BT + tid;            // float4 index over [64 rows][64 f4]
        int row = flat4 >> 6;
        int c4  = flat4 & 63;
        long long grow = n0 + row;
        if (grow >= N) grow = N - 1;
        float4 f = fvec[grow * 64 + c4];
        f16x4 h4;
        h4[0] = (_Float16)f.x; h4[1] = (_Float16)f.y;
        h4[2] = (_Float16)f.z; h4[3] = (_Float16)f.w;
        int off = row * 512 + ((c4 * 8) ^ ((row & 7) << 4));
        *(f16x4*)(smem + off) = h4;
    }
    __syncthreads();

    // ---- GEMM: acc[ct][p] -> col = ct*16+(lane&15), row = wv*16+(lane>>4)*4+p
    f32x4 acc[16];
    #pragma unroll
    for (int ct = 0; ct < 16; ++ct) {
        float b = bias[ct * 16 + (lane & 15)];
        acc[ct] = f32x4{b, b, b, b};
    }

    const int arow  = wv * 16 + (lane & 15);
    const int swzA  = (arow & 7) << 4;
    const int abase = arow * 512;
    const int kgrp  = (lane >> 4) * 16;

    #pragma unroll
    for (int kt = 0; kt < 8; ++kt) {
        int kbyte = kt * 64 + kgrp;
        f16x8 a8 = *(const f16x8*)(smem + abase + (kbyte ^ swzA));
        #pragma unroll
        for (int ct = 0; ct < 16; ++ct) {
            f16x8 bh = ws[(kt * 16 + ct) * 64 + lane];
            acc[ct] = __builtin_amdgcn_mfma_f32_16x16x32_f16(a8, bh, acc[ct], 0, 0, 0);
        }
    }

    // ---- row max per plane: 16 cts in-thread + DPP 16-lane reduce ----
    float M[4];
    #pragma unroll
    for (int p = 0; p < 4; ++p) {
        float m = acc[0][p];
        #pragma unroll
        for (int ct = 1; ct < 16; ++ct) m = fmaxf(m, acc[ct][p]);
        M[p] = row16_max(m);
    }

    // ---- one plane at a time: q-form peel, state = q[16] only -------------
    // q = E*z^5 (q0 = E). Per iter: S=sum(q); r=1-q/S; q *= r^5.
    // z recovered once at the end: z = exp2(0.2*log2(q) - le5),
    // le5 = 0.2*log2(E) = (acc-M)*LOG2E recomputed from acc (AGPR-parked).
    #pragma unroll 1
    for (int p = 0; p < 4; ++p) {
        float q[16];
        #pragma unroll
        for (int j = 0; j < 16; ++j)
            q[j] = __builtin_amdgcn_exp2f((acc[j][p] - M[p]) * EXP_C);

        #pragma unroll 1
        for (int it = 0; it < KSTEPS; ++it) {
            float s0 = ((q[0] + q[1]) + (q[2] + q[3]))
                     + ((q[4] + q[5]) + (q[6] + q[7]));
            float s1 = ((q[8] + q[9]) + (q[10] + q[11]))
                     + ((q[12] + q[13]) + (q[14] + q[15]));
            float s = row16_sum(s0 + s1);
            s = fmaxf(s, 1e-30f);
            float nr = -__builtin_amdgcn_rcpf(s);
            #pragma unroll
            for (int j = 0; j < 16; ++j) {
                float r  = fmaf(q[j], nr, 1.0f);   // 1 - q/S
                float r2 = r * r;
                float r4 = r2 * r2;
                q[j] *= r4 * r;                    // q *= r^5
            }
        }

        // epilogue: z = exp2(0.2*log2(q) - le5); out = f * z / (1-P)
        int row = wv * 16 + (lane >> 4) * 4 + p;
        long long grow = n0 + row;
        if (grow < N) {
            int swz = (row & 7) << 4;
            float* orow = out + grow * 256;
            #pragma unroll
            for (int j = 0; j < 16; ++j) {
                int col = j * 16 + (lane & 15);
                float le5 = (acc[j][p] - M[p]) * LOG2E;
                float qv  = fmaxf(q[j], 1e-38f);
                float zz  = __builtin_amdgcn_exp2f(
                    fmaf(__builtin_amdgcn_logf(qv), 0.2f, -le5));
                int off = row * 512 + ((col * 2) ^ swz);
                float fval = (float)(*(const _Float16*)(smem + off));
                orow[col] = fval * (zz * INV_1MP);
            }
        }
    }
}

extern "C" void kernel_launch(void* const* d_in, const int* in_sizes, int n_in,
                              void* d_out, int out_size, void* d_ws, size_t ws_size,
                              hipStream_t stream) {
    const float* feat = (const float*)d_in[0];
    const float* W    = (const float*)d_in[1];
    const float* bias = (const float*)d_in[2];
    float* out = (float*)d_out;
    int N = in_sizes[0] / DIMD;

    // 1) W -> frag-major fp16 in workspace (128 KB)
    w_conv_kernel<<<32, 256, 0, stream>>>(W, (f16x8*)d_ws);

    // 2) fused mask-GEMM + per-plane q-form peeling + output
    int grid = (int)((N + MT - 1) / MT);
    sad_mfma_kernel<<<grid, BT, 0, stream>>>(feat, bias, (const f16x8*)d_ws, out, N);
}

// Round 10
// 327.871 us; speedup vs baseline: 1.2176x; 1.1597x over previous
//
#include <hip/hip_runtime.h>
#include <hip/hip_bf16.h>
#include <math.h>

typedef _Float16 f16x8 __attribute__((ext_vector_type(8)));
typedef _Float16 f16x4 __attribute__((ext_vector_type(4)));
typedef float    f32x4 __attribute__((ext_vector_type(4)));
typedef float    f32x2 __attribute__((ext_vector_type(2)));

#define DIMD    256
#define MT      64          // rows per block
#define BT      256         // 4 waves; each wave owns 16 rows x 256 cols
#define KSTEPS  26
#define EXP_C   7.2134752044448170f   // log2(e)/TEMP, TEMP=0.2
#define LOG2E   1.4426950408889634f   // 0.2*EXP_C, for z-recovery
#define INV_1MP 1.1111111111111112f   // 1/(1-P), P=0.1

// ---- packed-f32 VALU helpers (VOP3P, full-rate 2x f32 on gfx950) ---------
static __device__ __forceinline__ f32x2 pk_fma(f32x2 a, f32x2 b, f32x2 c) {
    f32x2 d;
    asm("v_pk_fma_f32 %0, %1, %2, %3" : "=v"(d) : "v"(a), "v"(b), "v"(c));
    return d;
}
static __device__ __forceinline__ f32x2 pk_mul(f32x2 a, f32x2 b) {
    f32x2 d;
    asm("v_pk_mul_f32 %0, %1, %2" : "=v"(d) : "v"(a), "v"(b));
    return d;
}
static __device__ __forceinline__ f32x2 pk_add(f32x2 a, f32x2 b) {
    f32x2 d;
    asm("v_pk_add_f32 %0, %1, %2" : "=v"(d) : "v"(a), "v"(b));
    return d;
}

// ---- DPP row_ror cross-lane (16-lane groups, no DS ops) ------------------
template<int CTRL>
static __device__ __forceinline__ float dpp_ror(float s) {
    return __builtin_bit_cast(float, __builtin_amdgcn_update_dpp(
        0, __builtin_bit_cast(int, s), CTRL, 0xf, 0xf, false));
}
static __device__ __forceinline__ float row16_sum(float s) {
    s += dpp_ror<0x128>(s);   // ror:8
    s += dpp_ror<0x124>(s);   // ror:4
    s += dpp_ror<0x122>(s);   // ror:2
    s += dpp_ror<0x121>(s);   // ror:1
    return s;
}
static __device__ __forceinline__ float row16_max(float m) {
    m = fmaxf(m, dpp_ror<0x128>(m));
    m = fmaxf(m, dpp_ror<0x124>(m));
    m = fmaxf(m, dpp_ror<0x122>(m));
    m = fmaxf(m, dpp_ror<0x121>(m));
    return m;
}

// ---- pre-kernel: W[c][k] fp32 -> frag-major fp16 (single plane) ----------
// Tile (kt,ct): 64 lanes x 8 fp16. Lane l: col=ct*16+(l&15), k=kt*32+(l>>4)*8..+7
// ws: [128 tiles][64 lanes] = 128 KB
__global__ __launch_bounds__(256)
void w_conv_kernel(const float* __restrict__ W, f16x8* __restrict__ ws) {
    int gid  = blockIdx.x * 256 + threadIdx.x;   // 0..8191
    int tile = gid >> 6;                         // kt*16+ct
    int lane = gid & 63;
    int kt = tile >> 4, ct = tile & 15;
    int col = ct * 16 + (lane & 15);
    int k0  = kt * 32 + (lane >> 4) * 8;
    const float* wr = W + col * 256 + k0;
    float4 f01 = *(const float4*)wr;
    float4 f23 = *(const float4*)(wr + 4);
    float wv[8] = {f01.x, f01.y, f01.z, f01.w, f23.x, f23.y, f23.z, f23.w};
    f16x8 hi;
    #pragma unroll
    for (int j = 0; j < 8; ++j) hi[j] = (_Float16)wv[j];
    ws[tile * 64 + lane] = hi;
}

// ---- main fused kernel ----------------------------------------------------
// LDS: A fp16 [64 rows][256 cols], 32 KB, byte-XOR swizzle:
//   byte = row*512 + ((col*2) ^ ((row&7)<<4))
__global__ __launch_bounds__(BT, 4)
void sad_mfma_kernel(const float* __restrict__ feat,
                     const float* __restrict__ bias,
                     const f16x8* __restrict__ ws,
                     float* __restrict__ out,
                     int N)
{
    __shared__ __align__(16) unsigned char smem[MT * 512];  // 32 KB

    const int tid  = threadIdx.x;
    const int lane = tid & 63;
    const int wv   = tid >> 6;           // wave 0..3, owns rows wv*16..+15
    const long long n0 = (long long)blockIdx.x * MT;

    // ---- stage 64 feature rows -> fp16 LDS (swizzled) ----
    const float4* fvec = (const float4*)feat;
    #pragma unroll
    for (int i = 0; i < 16; ++i) {
        int flat4 = i * BT + tid;            // float4 index over [64 rows][64 f4]
        int row = flat4 >> 6;
        int c4  = flat4 & 63;
        long long grow = n0 + row;
        if (grow >= N) grow = N - 1;
        float4 f = fvec[grow * 64 + c4];
        f16x4 h4;
        h4[0] = (_Float16)f.x; h4[1] = (_Float16)f.y;
        h4[2] = (_Float16)f.z; h4[3] = (_Float16)f.w;
        int off = row * 512 + ((c4 * 8) ^ ((row & 7) << 4));
        *(f16x4*)(smem + off) = h4;
    }
    __syncthreads();

    // ---- GEMM: acc[ct][p] -> col = ct*16+(lane&15), row = wv*16+(lane>>4)*4+p
    f32x4 acc[16];
    #pragma unroll
    for (int ct = 0; ct < 16; ++ct) {
        float b = bias[ct * 16 + (lane & 15)];
        acc[ct] = f32x4{b, b, b, b};
    }

    const int arow  = wv * 16 + (lane & 15);
    const int swzA  = (arow & 7) << 4;
    const int abase = arow * 512;
    const int kgrp  = (lane >> 4) * 16;

    #pragma unroll
    for (int kt = 0; kt < 8; ++kt) {
        int kbyte = kt * 64 + kgrp;
        f16x8 a8 = *(const f16x8*)(smem + abase + (kbyte ^ swzA));
        #pragma unroll
        for (int ct = 0; ct < 16; ++ct) {
            f16x8 bh = ws[(kt * 16 + ct) * 64 + lane];
            acc[ct] = __builtin_amdgcn_mfma_f32_16x16x32_f16(a8, bh, acc[ct], 0, 0, 0);
        }
    }

    // ---- row max per plane: 16 cts in-thread + DPP 16-lane reduce ----
    float M[4];
    #pragma unroll
    for (int p = 0; p < 4; ++p) {
        float m = acc[0][p];
        #pragma unroll
        for (int ct = 1; ct < 16; ++ct) m = fmaxf(m, acc[ct][p]);
        M[p] = row16_max(m);
    }

    const f32x2 one2 = f32x2{1.0f, 1.0f};

    // ---- one plane at a time: q-form peel in packed f32 -------------------
    // q = E*z^5 (q0 = E). Per iter: S=sum(q); r=1-q/S; q *= r^5.
    // z recovered once at the end: z = exp2(0.2*log2(q) - le5),
    // le5 = (acc-M)*LOG2E recomputed from acc (AGPR-parked, free).
    #pragma unroll 1
    for (int p = 0; p < 4; ++p) {
        f32x2 q[8];
        #pragma unroll
        for (int cc = 0; cc < 8; ++cc) {
            q[cc] = f32x2{
                __builtin_amdgcn_exp2f((acc[2 * cc][p]     - M[p]) * EXP_C),
                __builtin_amdgcn_exp2f((acc[2 * cc + 1][p] - M[p]) * EXP_C)};
        }

        #pragma unroll 1
        for (int it = 0; it < KSTEPS; ++it) {
            f32x2 s2 = pk_add(pk_add(pk_add(q[0], q[1]), pk_add(q[2], q[3])),
                              pk_add(pk_add(q[4], q[5]), pk_add(q[6], q[7])));
            float s = row16_sum(s2.x + s2.y);
            s = fmaxf(s, 1e-30f);
            float nr = -__builtin_amdgcn_rcpf(s);
            f32x2 nrv = f32x2{nr, nr};
            #pragma unroll
            for (int cc = 0; cc < 8; ++cc) {
                f32x2 r  = pk_fma(q[cc], nrv, one2);   // 1 - q/S
                f32x2 r2 = pk_mul(r, r);
                f32x2 r4 = pk_mul(r2, r2);
                f32x2 r5 = pk_mul(r4, r);
                q[cc] = pk_mul(q[cc], r5);             // q *= r^5
            }
        }

        // epilogue: z = exp2(0.2*log2(q) - le5); out = f * z / (1-P)
        int row = wv * 16 + (lane >> 4) * 4 + p;
        long long grow = n0 + row;
        if (grow < N) {
            int swz = (row & 7) << 4;
            float* orow = out + grow * 256;
            #pragma unroll
            for (int cc = 0; cc < 8; ++cc) {
                #pragma unroll
                for (int h = 0; h < 2; ++h) {
                    int col = (2 * cc + h) * 16 + (lane & 15);
                    float le5 = (acc[2 * cc + h][p] - M[p]) * LOG2E;
                    float qv  = fmaxf(h ? q[cc].y : q[cc].x, 1e-38f);
                    float zz  = __builtin_amdgcn_exp2f(
                        fmaf(__builtin_amdgcn_logf(qv), 0.2f, -le5));
                    int off = row * 512 + ((col * 2) ^ swz);
                    float fval = (float)(*(const _Float16*)(smem + off));
                    orow[col] = fval * (zz * INV_1MP);
                }
            }
        }
    }
}

extern "C" void kernel_launch(void* const* d_in, const int* in_sizes, int n_in,
                              void* d_out, int out_size, void* d_ws, size_t ws_size,
                              hipStream_t stream) {
    const float* feat = (const float*)d_in[0];
    const float* W    = (const float*)d_in[1];
    const float* bias = (const float*)d_in[2];
    float* out = (float*)d_out;
    int N = in_sizes[0] / DIMD;

    // 1) W -> frag-major fp16 in workspace (128 KB)
    w_conv_kernel<<<32, 256, 0, stream>>>(W, (f16x8*)d_ws);

    // 2) fused mask-GEMM + per-plane q-form pk-f32 peeling + output
    int grid = (int)((N + MT - 1) / MT);
    sad_mfma_kernel<<<grid, BT, 0, stream>>>(feat, bias, (const f16x8*)d_ws, out, N);
}